// Round 3
// baseline (2292.023 us; speedup 1.0000x reference)
//
#include <hip/hip_runtime.h>
#include <hip/hip_bf16.h>
#include <math.h>

#define N_VOTERS 1048576
#define NUM_CAND 32
#define EMB 128
#define NUM_ELEC 4096

typedef unsigned short u16;
typedef unsigned int u32;
typedef __attribute__((ext_vector_type(8))) short bf16x8;
typedef __attribute__((ext_vector_type(4))) short short4v;
typedef __attribute__((ext_vector_type(4))) float f32x4;

__device__ __forceinline__ u16 f2bf(float f) {   // RNE (prep only)
    union { float f; u32 u; } v; v.f = f;
    u32 r = v.u + 0x7FFFu + ((v.u >> 16) & 1u);
    return (u16)(r >> 16);
}
// pack two floats to bf16 (round-half-up): f0 -> low16, f1 -> high16
__device__ __forceinline__ u32 pkbf(float f0, float f1) {
    u32 u0 = __float_as_uint(f0) + 0x8000u;
    u32 u1 = __float_as_uint(f1) + 0x8000u;
    return __builtin_amdgcn_perm(u1, u0, 0x07060302u);
}

// ---------------- Kernel A: transpose+convert local weights to bf16 ----------------
__global__ void prep_weights(const float* __restrict__ lW1, const float* __restrict__ lW2,
                             const float* __restrict__ lW3,
                             u16* __restrict__ w1t, u16* __restrict__ w2t, u16* __restrict__ w3t) {
    int tid = blockIdx.x * blockDim.x + threadIdx.x;  // 0..16383
    if (tid < 4096) {
        int n = tid >> 5, k = tid & 31;
        w1t[tid] = f2bf(lW1[k * EMB + n]);
    }
    {
        int n = tid >> 7, k = tid & 127;
        w2t[tid] = f2bf(lW2[k * EMB + n]);
        w3t[tid] = f2bf(lW3[k * EMB + n]);
    }
}

// ---------------- Kernel B: fused local MLP + in-register segment sum ----------------
// 256 thr = 4 waves, 64 voters/block. Wave wv owns features wv*32..+31.
// L3 D-layout: lane(qd,l15) holds 8 features (wv*32+t*16+qd*4+r) of voter l15 -> register
// segment accumulation (sorted index), flush = per-lane partial atomics, bias folded as bias*cnt.
__global__ __launch_bounds__(256, 4) void local_fused(
    const float* __restrict__ x, const int* __restrict__ idx,
    const float* __restrict__ lb1, const float* __restrict__ lb2, const float* __restrict__ lb3,
    const u16* __restrict__ w1t, const u16* __restrict__ w2t, const u16* __restrict__ w3t,
    float* __restrict__ agg)
{
    constexpr int XSTR = 36;   // x tile stride (72B rows, 8B-aligned b64 reads)
    constexpr int ASTR = 136;  // act stride (272B rows, 16B-aligned b128 reads)
    __shared__ __align__(16) u16 smem[64 * XSTR + 2 * 64 * ASTR];   // 39424 B
    __shared__ int segs[64];
    u16* bufX = smem;
    u16* act1 = smem + 64 * XSTR;
    u16* act2 = act1 + 64 * ASTR;

    const int tid = threadIdx.x;
    const int v0 = blockIdx.x * 64;
    const int lane = tid & 63;
    const int wv = tid >> 6;
    const int qd = lane >> 4;
    const int l15 = lane & 15;
    const int mrow0 = wv * 32 + l15;

    // ---- stage x [64][32] fp32 -> bf16 LDS ----
    {
        const float4* xin = (const float4*)(x + (size_t)v0 * NUM_CAND);
        #pragma unroll
        for (int i = 0; i < 2; ++i) {
            int F = i * 256 + tid;
            float4 v = xin[F];
            int row = F >> 3, c4 = (F & 7) * 4;
            uint2 pv; pv.x = pkbf(v.x, v.y); pv.y = pkbf(v.z, v.w);
            *(uint2*)(bufX + row * XSTR + c4) = pv;
        }
        if (tid < 64) segs[tid] = idx[v0 + tid];
    }

    bf16x8 wa0 = *(const bf16x8*)(w1t + mrow0 * 32 + qd * 8);
    bf16x8 wa1 = *(const bf16x8*)(w1t + (mrow0 + 16) * 32 + qd * 8);
    f32x4 bA1 = *(const f32x4*)(lb1 + wv * 32 + qd * 4);
    f32x4 bB1 = *(const f32x4*)(lb1 + wv * 32 + 16 + qd * 4);
    __syncthreads();

    // ---- layer 1 (K=32): bufX -> act1 ----
    #pragma unroll
    for (int nt = 0; nt < 4; ++nt) {
        int vr = nt * 16 + l15;
        union { bf16x8 v; short4v h[2]; } b;
        b.h[0] = *(const short4v*)(bufX + vr * XSTR + qd * 8);
        b.h[1] = *(const short4v*)(bufX + vr * XSTR + qd * 8 + 4);
        f32x4 z = {0.f, 0.f, 0.f, 0.f};
        f32x4 a0 = __builtin_amdgcn_mfma_f32_16x16x32_bf16(wa0, b.v, z, 0, 0, 0);
        f32x4 a1 = __builtin_amdgcn_mfma_f32_16x16x32_bf16(wa1, b.v, z, 0, 0, 0);
        uint2 s0; s0.x = pkbf(fmaxf(a0[0] + bA1[0], 0.f), fmaxf(a0[1] + bA1[1], 0.f));
        s0.y = pkbf(fmaxf(a0[2] + bA1[2], 0.f), fmaxf(a0[3] + bA1[3], 0.f));
        *(uint2*)(act1 + vr * ASTR + wv * 32 + qd * 4) = s0;
        uint2 s1; s1.x = pkbf(fmaxf(a1[0] + bB1[0], 0.f), fmaxf(a1[1] + bB1[1], 0.f));
        s1.y = pkbf(fmaxf(a1[2] + bB1[2], 0.f), fmaxf(a1[3] + bB1[3], 0.f));
        *(uint2*)(act1 + vr * ASTR + wv * 32 + 16 + qd * 4) = s1;
    }

    bf16x8 w2a[2][4];
    #pragma unroll
    for (int t = 0; t < 2; ++t)
        #pragma unroll
        for (int kk = 0; kk < 4; ++kk)
            w2a[t][kk] = *(const bf16x8*)(w2t + (mrow0 + t * 16) * 128 + kk * 32 + qd * 8);
    f32x4 bA2 = *(const f32x4*)(lb2 + wv * 32 + qd * 4);
    f32x4 bB2 = *(const f32x4*)(lb2 + wv * 32 + 16 + qd * 4);
    __syncthreads();

    // ---- layer 2 (K=128): act1 -> act2 ----
    #pragma unroll
    for (int nt = 0; nt < 4; ++nt) {
        int vr = nt * 16 + l15;
        f32x4 a0 = {0.f, 0.f, 0.f, 0.f}, a1 = {0.f, 0.f, 0.f, 0.f};
        #pragma unroll
        for (int kk = 0; kk < 4; ++kk) {
            bf16x8 b = *(const bf16x8*)(act1 + vr * ASTR + kk * 32 + qd * 8);
            a0 = __builtin_amdgcn_mfma_f32_16x16x32_bf16(w2a[0][kk], b, a0, 0, 0, 0);
            a1 = __builtin_amdgcn_mfma_f32_16x16x32_bf16(w2a[1][kk], b, a1, 0, 0, 0);
        }
        uint2 s0; s0.x = pkbf(fmaxf(a0[0] + bA2[0], 0.f), fmaxf(a0[1] + bA2[1], 0.f));
        s0.y = pkbf(fmaxf(a0[2] + bA2[2], 0.f), fmaxf(a0[3] + bA2[3], 0.f));
        *(uint2*)(act2 + vr * ASTR + wv * 32 + qd * 4) = s0;
        uint2 s1; s1.x = pkbf(fmaxf(a1[0] + bB2[0], 0.f), fmaxf(a1[1] + bB2[1], 0.f));
        s1.y = pkbf(fmaxf(a1[2] + bB2[2], 0.f), fmaxf(a1[3] + bB2[3], 0.f));
        *(uint2*)(act2 + vr * ASTR + wv * 32 + 16 + qd * 4) = s1;
    }

    bf16x8 w3a[2][4];
    #pragma unroll
    for (int t = 0; t < 2; ++t)
        #pragma unroll
        for (int kk = 0; kk < 4; ++kk)
            w3a[t][kk] = *(const bf16x8*)(w3t + (mrow0 + t * 16) * 128 + kk * 32 + qd * 8);
    f32x4 bA3 = *(const f32x4*)(lb3 + wv * 32 + qd * 4);
    f32x4 bB3 = *(const f32x4*)(lb3 + wv * 32 + 16 + qd * 4);
    __syncthreads();

    // ---- layer 3 (K=128) + in-register segment accumulation ----
    float fs0[4] = {0.f, 0.f, 0.f, 0.f}, fs1[4] = {0.f, 0.f, 0.f, 0.f};
    int cnt = 0;
    int cur = segs[0];
    float* const aggb = agg + (size_t)wv * 32 + qd * 4;

    #pragma unroll
    for (int nt = 0; nt < 4; ++nt) {
        int vr = nt * 16 + l15;
        f32x4 a0 = {0.f, 0.f, 0.f, 0.f}, a1 = {0.f, 0.f, 0.f, 0.f};
        #pragma unroll
        for (int kk = 0; kk < 4; ++kk) {
            bf16x8 b = *(const bf16x8*)(act2 + vr * ASTR + kk * 32 + qd * 8);
            a0 = __builtin_amdgcn_mfma_f32_16x16x32_bf16(w3a[0][kk], b, a0, 0, 0, 0);
            a1 = __builtin_amdgcn_mfma_f32_16x16x32_bf16(w3a[1][kk], b, a1, 0, 0, 0);
        }
        int sg = segs[nt * 16 + l15];
        int first = __builtin_amdgcn_readfirstlane(sg);
        unsigned long long bal = __ballot(sg == first);
        if (bal == ~0ull) {                    // all 16 voters in this tile share one segment
            if (first != cur) {
                if (cnt > 0) {                 // flush: per-lane partial atomics, bias*cnt
                    float c = (float)cnt;
                    float* p = aggb + (size_t)cur * EMB;
                    #pragma unroll
                    for (int r = 0; r < 4; ++r) atomicAdd(p + r,      fmaf(bA3[r], c, fs0[r]));
                    #pragma unroll
                    for (int r = 0; r < 4; ++r) atomicAdd(p + 16 + r, fmaf(bB3[r], c, fs1[r]));
                    #pragma unroll
                    for (int r = 0; r < 4; ++r) { fs0[r] = 0.f; fs1[r] = 0.f; }
                    cnt = 0;
                }
                cur = first;
            }
            #pragma unroll
            for (int r = 0; r < 4; ++r) { fs0[r] += a0[r]; fs1[r] += a1[r]; }
            ++cnt;
        } else {                               // rare: boundary inside the 16-voter tile
            if (cnt > 0) {
                float c = (float)cnt;
                float* p = aggb + (size_t)cur * EMB;
                #pragma unroll
                for (int r = 0; r < 4; ++r) atomicAdd(p + r,      fmaf(bA3[r], c, fs0[r]));
                #pragma unroll
                for (int r = 0; r < 4; ++r) atomicAdd(p + 16 + r, fmaf(bB3[r], c, fs1[r]));
                #pragma unroll
                for (int r = 0; r < 4; ++r) { fs0[r] = 0.f; fs1[r] = 0.f; }
                cnt = 0;
            }
            float v0[4], v1[4];
            #pragma unroll
            for (int r = 0; r < 4; ++r) { v0[r] = a0[r] + bA3[r]; v1[r] = a1[r] + bB3[r]; }
            // segmented inclusive scan over the 16 voter lanes (index sorted -> masking safe)
            #pragma unroll
            for (int d = 1; d < 16; d <<= 1) {
                int so = __shfl_up(sg, d, 16);
                bool ok = (l15 >= d) && (so == sg);
                #pragma unroll
                for (int r = 0; r < 4; ++r) {
                    float o0 = __shfl_up(v0[r], d, 16); if (ok) v0[r] += o0;
                    float o1 = __shfl_up(v1[r], d, 16); if (ok) v1[r] += o1;
                }
            }
            int sgn = __shfl_down(sg, 1, 16);   // lane 15: returns own -> guarded below
            bool isend = (l15 == 15) || (sgn != sg);
            if (isend) {
                float* p = aggb + (size_t)sg * EMB;
                #pragma unroll
                for (int r = 0; r < 4; ++r) atomicAdd(p + r,      v0[r]);
                #pragma unroll
                for (int r = 0; r < 4; ++r) atomicAdd(p + 16 + r, v1[r]);
            }
            cur = __shfl(sg, 15, 16);           // run of last voter continues into next tile
        }
    }
    if (cnt > 0) {
        float c = (float)cnt;
        float* p = aggb + (size_t)cur * EMB;
        #pragma unroll
        for (int r = 0; r < 4; ++r) atomicAdd(p + r,      fmaf(bA3[r], c, fs0[r]));
        #pragma unroll
        for (int r = 0; r < 4; ++r) atomicAdd(p + 16 + r, fmaf(bB3[r], c, fs1[r]));
    }
}

// ---------------- Kernel C: global MLP + log_softmax (fp32) ----------------
__global__ __launch_bounds__(256) void global_mlp(
    const float* __restrict__ agg,
    const float* __restrict__ gW1, const float* __restrict__ gb1,
    const float* __restrict__ gW2, const float* __restrict__ gb2,
    const float* __restrict__ gW3, const float* __restrict__ gb3,
    float* __restrict__ out)
{
    __shared__ float actA[8 * 128];
    __shared__ float actB[8 * 128];
    __shared__ float sc[8 * 32];
    const int tid = threadIdx.x;
    const int s0 = blockIdx.x * 8;

    #pragma unroll
    for (int i = 0; i < 4; ++i) {
        int f = i * 256 + tid;
        actA[f] = agg[(size_t)s0 * 128 + f];
    }
    __syncthreads();

    const int j = tid & 127, g = tid >> 7;
    {
        float acc[4];
        #pragma unroll
        for (int si = 0; si < 4; ++si) acc[si] = gb1[j];
        #pragma unroll 8
        for (int k = 0; k < 128; ++k) {
            float w = gW1[k * 128 + j];
            #pragma unroll
            for (int si = 0; si < 4; ++si) acc[si] += actA[(g * 4 + si) * 128 + k] * w;
        }
        #pragma unroll
        for (int si = 0; si < 4; ++si) actB[(g * 4 + si) * 128 + j] = fmaxf(acc[si], 0.f);
    }
    __syncthreads();
    {
        float acc[4];
        #pragma unroll
        for (int si = 0; si < 4; ++si) acc[si] = gb2[j];
        #pragma unroll 8
        for (int k = 0; k < 128; ++k) {
            float w = gW2[k * 128 + j];
            #pragma unroll
            for (int si = 0; si < 4; ++si) acc[si] += actB[(g * 4 + si) * 128 + k] * w;
        }
        #pragma unroll
        for (int si = 0; si < 4; ++si) actA[(g * 4 + si) * 128 + j] = fmaxf(acc[si], 0.f);
    }
    __syncthreads();
    {
        int c = tid & 31, sg = tid >> 5;
        float a3 = gb3[c];
        #pragma unroll 8
        for (int k = 0; k < 128; ++k) a3 += actA[sg * 128 + k] * gW3[k * 32 + c];
        sc[sg * 32 + c] = a3;
    }
    __syncthreads();
    {
        int c = tid & 31, sg = tid >> 5;
        float v = sc[sg * 32 + c];
        float m = v;
        #pragma unroll
        for (int off = 16; off >= 1; off >>= 1) m = fmaxf(m, __shfl_xor(m, off, 32));
        float e = expf(v - m);
        float sum = e;
        #pragma unroll
        for (int off = 16; off >= 1; off >>= 1) sum += __shfl_xor(sum, off, 32);
        out[(size_t)(s0 + sg) * 32 + c] = (v - m) - logf(sum);
    }
}

extern "C" void kernel_launch(void* const* d_in, const int* in_sizes, int n_in,
                              void* d_out, int out_size, void* d_ws, size_t ws_size,
                              hipStream_t stream) {
    const float* x   = (const float*)d_in[0];
    const int*   idx = (const int*)d_in[1];
    const float* lW1 = (const float*)d_in[2];
    const float* lb1 = (const float*)d_in[3];
    const float* lW2 = (const float*)d_in[4];
    const float* lb2 = (const float*)d_in[5];
    const float* lW3 = (const float*)d_in[6];
    const float* lb3 = (const float*)d_in[7];
    const float* gW1 = (const float*)d_in[8];
    const float* gb1 = (const float*)d_in[9];
    const float* gW2 = (const float*)d_in[10];
    const float* gb2 = (const float*)d_in[11];
    const float* gW3 = (const float*)d_in[12];
    const float* gb3 = (const float*)d_in[13];
    float* out = (float*)d_out;

    float* agg = (float*)d_ws;                                  // [4096][128] fp32 = 2 MB
    u16* w1t = (u16*)((char*)d_ws + (size_t)NUM_ELEC * EMB * 4);
    u16* w2t = w1t + 128 * 32;
    u16* w3t = w2t + 128 * 128;

    hipMemsetAsync(d_ws, 0, (size_t)NUM_ELEC * EMB * sizeof(float), stream);
    prep_weights<<<64, 256, 0, stream>>>(lW1, lW2, lW3, w1t, w2t, w3t);
    local_fused<<<N_VOTERS / 64, 256, 0, stream>>>(x, idx, lb1, lb2, lb3, w1t, w2t, w3t, agg);
    global_mlp<<<NUM_ELEC / 8, 256, 0, stream>>>(agg, gW1, gb1, gW2, gb2, gW3, gb3, out);
}

// Round 4
// 352.179 us; speedup vs baseline: 6.5081x; 6.5081x over previous
//
#include <hip/hip_runtime.h>
#include <hip/hip_bf16.h>
#include <math.h>

#define N_VOTERS 1048576
#define NUM_CAND 32
#define EMB 128
#define NUM_ELEC 4096

typedef unsigned short u16;
typedef unsigned int u32;
typedef __attribute__((ext_vector_type(8))) short bf16x8;
typedef __attribute__((ext_vector_type(4))) short short4v;
typedef __attribute__((ext_vector_type(4))) float f32x4;

__device__ __forceinline__ u16 f2bf(float f) {   // RNE (prep only)
    union { float f; u32 u; } v; v.f = f;
    u32 r = v.u + 0x7FFFu + ((v.u >> 16) & 1u);
    return (u16)(r >> 16);
}
// pack two floats to bf16 (round-half-up): f0 -> low16, f1 -> high16
__device__ __forceinline__ u32 pkbf(float f0, float f1) {
    u32 u0 = __float_as_uint(f0) + 0x8000u;
    u32 u1 = __float_as_uint(f1) + 0x8000u;
    return __builtin_amdgcn_perm(u1, u0, 0x07060302u);
}

// ---------------- Kernel A: transpose+convert local weights to bf16 ----------------
__global__ void prep_weights(const float* __restrict__ lW1, const float* __restrict__ lW2,
                             const float* __restrict__ lW3,
                             u16* __restrict__ w1t, u16* __restrict__ w2t, u16* __restrict__ w3t) {
    int tid = blockIdx.x * blockDim.x + threadIdx.x;  // 0..16383
    if (tid < 4096) {
        int n = tid >> 5, k = tid & 31;
        w1t[tid] = f2bf(lW1[k * EMB + n]);
    }
    {
        int n = tid >> 7, k = tid & 127;
        w2t[tid] = f2bf(lW2[k * EMB + n]);
        w3t[tid] = f2bf(lW3[k * EMB + n]);
    }
}

// ---------------- Kernel B: fused local MLP + in-register segment sum ----------------
// 256 thr = 4 waves, 64 voters/block. Wave wv owns features wv*32..+31.
// Tail: register accumulation per lane (one voter each), then butterfly-reduce across the
// 16 voter-lanes BEFORE atomics -> only l15==0 lanes issue atomics (32/wave-flush, ~2.6M total).
__global__ __launch_bounds__(256, 4) void local_fused(
    const float* __restrict__ x, const int* __restrict__ idx,
    const float* __restrict__ lb1, const float* __restrict__ lb2, const float* __restrict__ lb3,
    const u16* __restrict__ w1t, const u16* __restrict__ w2t, const u16* __restrict__ w3t,
    float* __restrict__ agg)
{
    constexpr int XSTR = 36;   // x tile stride (72B rows, 8B-aligned b64 reads)
    constexpr int ASTR = 136;  // act stride (272B rows, 16B-aligned b128 reads)
    __shared__ __align__(16) u16 smem[64 * XSTR + 2 * 64 * ASTR];   // 39424 B
    __shared__ int segs[64];
    u16* bufX = smem;
    u16* act1 = smem + 64 * XSTR;
    u16* act2 = act1 + 64 * ASTR;

    const int tid = threadIdx.x;
    const int v0 = blockIdx.x * 64;
    const int lane = tid & 63;
    const int wv = tid >> 6;
    const int qd = lane >> 4;
    const int l15 = lane & 15;
    const int mrow0 = wv * 32 + l15;

    // ---- stage x [64][32] fp32 -> bf16 LDS ----
    {
        const float4* xin = (const float4*)(x + (size_t)v0 * NUM_CAND);
        #pragma unroll
        for (int i = 0; i < 2; ++i) {
            int F = i * 256 + tid;
            float4 v = xin[F];
            int row = F >> 3, c4 = (F & 7) * 4;
            uint2 pv; pv.x = pkbf(v.x, v.y); pv.y = pkbf(v.z, v.w);
            *(uint2*)(bufX + row * XSTR + c4) = pv;
        }
        if (tid < 64) segs[tid] = idx[v0 + tid];
    }

    bf16x8 wa0 = *(const bf16x8*)(w1t + mrow0 * 32 + qd * 8);
    bf16x8 wa1 = *(const bf16x8*)(w1t + (mrow0 + 16) * 32 + qd * 8);
    f32x4 bA1 = *(const f32x4*)(lb1 + wv * 32 + qd * 4);
    f32x4 bB1 = *(const f32x4*)(lb1 + wv * 32 + 16 + qd * 4);
    __syncthreads();

    // ---- layer 1 (K=32): bufX -> act1 ----
    #pragma unroll
    for (int nt = 0; nt < 4; ++nt) {
        int vr = nt * 16 + l15;
        union { bf16x8 v; short4v h[2]; } b;
        b.h[0] = *(const short4v*)(bufX + vr * XSTR + qd * 8);
        b.h[1] = *(const short4v*)(bufX + vr * XSTR + qd * 8 + 4);
        f32x4 z = {0.f, 0.f, 0.f, 0.f};
        f32x4 a0 = __builtin_amdgcn_mfma_f32_16x16x32_bf16(wa0, b.v, z, 0, 0, 0);
        f32x4 a1 = __builtin_amdgcn_mfma_f32_16x16x32_bf16(wa1, b.v, z, 0, 0, 0);
        uint2 s0; s0.x = pkbf(fmaxf(a0[0] + bA1[0], 0.f), fmaxf(a0[1] + bA1[1], 0.f));
        s0.y = pkbf(fmaxf(a0[2] + bA1[2], 0.f), fmaxf(a0[3] + bA1[3], 0.f));
        *(uint2*)(act1 + vr * ASTR + wv * 32 + qd * 4) = s0;
        uint2 s1; s1.x = pkbf(fmaxf(a1[0] + bB1[0], 0.f), fmaxf(a1[1] + bB1[1], 0.f));
        s1.y = pkbf(fmaxf(a1[2] + bB1[2], 0.f), fmaxf(a1[3] + bB1[3], 0.f));
        *(uint2*)(act1 + vr * ASTR + wv * 32 + 16 + qd * 4) = s1;
    }

    bf16x8 w2a[2][4];
    #pragma unroll
    for (int t = 0; t < 2; ++t)
        #pragma unroll
        for (int kk = 0; kk < 4; ++kk)
            w2a[t][kk] = *(const bf16x8*)(w2t + (mrow0 + t * 16) * 128 + kk * 32 + qd * 8);
    f32x4 bA2 = *(const f32x4*)(lb2 + wv * 32 + qd * 4);
    f32x4 bB2 = *(const f32x4*)(lb2 + wv * 32 + 16 + qd * 4);
    __syncthreads();

    // ---- layer 2 (K=128): act1 -> act2 ----
    #pragma unroll
    for (int nt = 0; nt < 4; ++nt) {
        int vr = nt * 16 + l15;
        f32x4 a0 = {0.f, 0.f, 0.f, 0.f}, a1 = {0.f, 0.f, 0.f, 0.f};
        #pragma unroll
        for (int kk = 0; kk < 4; ++kk) {
            bf16x8 b = *(const bf16x8*)(act1 + vr * ASTR + kk * 32 + qd * 8);
            a0 = __builtin_amdgcn_mfma_f32_16x16x32_bf16(w2a[0][kk], b, a0, 0, 0, 0);
            a1 = __builtin_amdgcn_mfma_f32_16x16x32_bf16(w2a[1][kk], b, a1, 0, 0, 0);
        }
        uint2 s0; s0.x = pkbf(fmaxf(a0[0] + bA2[0], 0.f), fmaxf(a0[1] + bA2[1], 0.f));
        s0.y = pkbf(fmaxf(a0[2] + bA2[2], 0.f), fmaxf(a0[3] + bA2[3], 0.f));
        *(uint2*)(act2 + vr * ASTR + wv * 32 + qd * 4) = s0;
        uint2 s1; s1.x = pkbf(fmaxf(a1[0] + bB2[0], 0.f), fmaxf(a1[1] + bB2[1], 0.f));
        s1.y = pkbf(fmaxf(a1[2] + bB2[2], 0.f), fmaxf(a1[3] + bB2[3], 0.f));
        *(uint2*)(act2 + vr * ASTR + wv * 32 + 16 + qd * 4) = s1;
    }

    bf16x8 w3a[2][4];
    #pragma unroll
    for (int t = 0; t < 2; ++t)
        #pragma unroll
        for (int kk = 0; kk < 4; ++kk)
            w3a[t][kk] = *(const bf16x8*)(w3t + (mrow0 + t * 16) * 128 + kk * 32 + qd * 8);
    f32x4 bA3 = *(const f32x4*)(lb3 + wv * 32 + qd * 4);
    f32x4 bB3 = *(const f32x4*)(lb3 + wv * 32 + 16 + qd * 4);
    __syncthreads();

    // ---- layer 3 (K=128) + in-register segment accumulation ----
    float fs0[4] = {0.f, 0.f, 0.f, 0.f}, fs1[4] = {0.f, 0.f, 0.f, 0.f};
    int cnt = 0;
    int cur = segs[0];
    float* const aggb = agg + (size_t)wv * 32 + qd * 4;

    // flush: butterfly-reduce fs over the 16 voter-lanes, then l15==0 lanes issue atomics.
    // All 64 lanes must be active (call only from wave-uniform control flow).
    auto flush = [&]() {
        float t[8];
        #pragma unroll
        for (int r = 0; r < 4; ++r) { t[r] = fs0[r]; t[4 + r] = fs1[r]; }
        #pragma unroll
        for (int d = 1; d < 16; d <<= 1)
            #pragma unroll
            for (int r = 0; r < 8; ++r) t[r] += __shfl_xor(t[r], d, 16);
        if (l15 == 0) {
            float c = (float)(cnt * 16);          // run length in voters
            float* p = aggb + (size_t)cur * EMB;
            #pragma unroll
            for (int r = 0; r < 4; ++r) atomicAdd(p + r,      fmaf(bA3[r], c, t[r]));
            #pragma unroll
            for (int r = 0; r < 4; ++r) atomicAdd(p + 16 + r, fmaf(bB3[r], c, t[4 + r]));
        }
        #pragma unroll
        for (int r = 0; r < 4; ++r) { fs0[r] = 0.f; fs1[r] = 0.f; }
        cnt = 0;
    };

    #pragma unroll
    for (int nt = 0; nt < 4; ++nt) {
        int vr = nt * 16 + l15;
        f32x4 a0 = {0.f, 0.f, 0.f, 0.f}, a1 = {0.f, 0.f, 0.f, 0.f};
        #pragma unroll
        for (int kk = 0; kk < 4; ++kk) {
            bf16x8 b = *(const bf16x8*)(act2 + vr * ASTR + kk * 32 + qd * 8);
            a0 = __builtin_amdgcn_mfma_f32_16x16x32_bf16(w3a[0][kk], b, a0, 0, 0, 0);
            a1 = __builtin_amdgcn_mfma_f32_16x16x32_bf16(w3a[1][kk], b, a1, 0, 0, 0);
        }
        int sg = segs[nt * 16 + l15];
        int first = __builtin_amdgcn_readfirstlane(sg);
        unsigned long long bal = __ballot(sg == first);
        if (bal == ~0ull) {                    // all 16 voters in this tile share one segment
            if (first != cur) {
                if (cnt > 0) flush();
                cur = first;
            }
            #pragma unroll
            for (int r = 0; r < 4; ++r) { fs0[r] += a0[r]; fs1[r] += a1[r]; }
            ++cnt;
        } else {                               // rare: boundary inside the 16-voter tile
            if (cnt > 0) flush();
            float v0a[4], v1a[4];
            #pragma unroll
            for (int r = 0; r < 4; ++r) { v0a[r] = a0[r] + bA3[r]; v1a[r] = a1[r] + bB3[r]; }
            // segmented inclusive scan over the 16 voter lanes (sorted index -> masking safe)
            #pragma unroll
            for (int d = 1; d < 16; d <<= 1) {
                int so = __shfl_up(sg, d, 16);
                bool ok = (l15 >= d) && (so == sg);
                #pragma unroll
                for (int r = 0; r < 4; ++r) {
                    float o0 = __shfl_up(v0a[r], d, 16); if (ok) v0a[r] += o0;
                    float o1 = __shfl_up(v1a[r], d, 16); if (ok) v1a[r] += o1;
                }
            }
            int sgn = __shfl_down(sg, 1, 16);
            bool isend = (l15 == 15) || (sgn != sg);
            if (isend) {                        // one lane per run per qd: distinct addresses
                float* p = aggb + (size_t)sg * EMB;
                #pragma unroll
                for (int r = 0; r < 4; ++r) atomicAdd(p + r,      v0a[r]);
                #pragma unroll
                for (int r = 0; r < 4; ++r) atomicAdd(p + 16 + r, v1a[r]);
            }
            cur = __shfl(sg, 15, 16);           // last voter's run continues into next tile
        }
    }
    if (cnt > 0) flush();
}

// ---------------- Kernel C: global MLP + log_softmax (fp32) ----------------
__global__ __launch_bounds__(256) void global_mlp(
    const float* __restrict__ agg,
    const float* __restrict__ gW1, const float* __restrict__ gb1,
    const float* __restrict__ gW2, const float* __restrict__ gb2,
    const float* __restrict__ gW3, const float* __restrict__ gb3,
    float* __restrict__ out)
{
    __shared__ float actA[8 * 128];
    __shared__ float actB[8 * 128];
    __shared__ float sc[8 * 32];
    const int tid = threadIdx.x;
    const int s0 = blockIdx.x * 8;

    #pragma unroll
    for (int i = 0; i < 4; ++i) {
        int f = i * 256 + tid;
        actA[f] = agg[(size_t)s0 * 128 + f];
    }
    __syncthreads();

    const int j = tid & 127, g = tid >> 7;
    {
        float acc[4];
        #pragma unroll
        for (int si = 0; si < 4; ++si) acc[si] = gb1[j];
        #pragma unroll 8
        for (int k = 0; k < 128; ++k) {
            float w = gW1[k * 128 + j];
            #pragma unroll
            for (int si = 0; si < 4; ++si) acc[si] += actA[(g * 4 + si) * 128 + k] * w;
        }
        #pragma unroll
        for (int si = 0; si < 4; ++si) actB[(g * 4 + si) * 128 + j] = fmaxf(acc[si], 0.f);
    }
    __syncthreads();
    {
        float acc[4];
        #pragma unroll
        for (int si = 0; si < 4; ++si) acc[si] = gb2[j];
        #pragma unroll 8
        for (int k = 0; k < 128; ++k) {
            float w = gW2[k * 128 + j];
            #pragma unroll
            for (int si = 0; si < 4; ++si) acc[si] += actB[(g * 4 + si) * 128 + k] * w;
        }
        #pragma unroll
        for (int si = 0; si < 4; ++si) actA[(g * 4 + si) * 128 + j] = fmaxf(acc[si], 0.f);
    }
    __syncthreads();
    {
        int c = tid & 31, sg = tid >> 5;
        float a3 = gb3[c];
        #pragma unroll 8
        for (int k = 0; k < 128; ++k) a3 += actA[sg * 128 + k] * gW3[k * 32 + c];
        sc[sg * 32 + c] = a3;
    }
    __syncthreads();
    {
        int c = tid & 31, sg = tid >> 5;
        float v = sc[sg * 32 + c];
        float m = v;
        #pragma unroll
        for (int off = 16; off >= 1; off >>= 1) m = fmaxf(m, __shfl_xor(m, off, 32));
        float e = expf(v - m);
        float sum = e;
        #pragma unroll
        for (int off = 16; off >= 1; off >>= 1) sum += __shfl_xor(sum, off, 32);
        out[(size_t)(s0 + sg) * 32 + c] = (v - m) - logf(sum);
    }
}

extern "C" void kernel_launch(void* const* d_in, const int* in_sizes, int n_in,
                              void* d_out, int out_size, void* d_ws, size_t ws_size,
                              hipStream_t stream) {
    const float* x   = (const float*)d_in[0];
    const int*   idx = (const int*)d_in[1];
    const float* lW1 = (const float*)d_in[2];
    const float* lb1 = (const float*)d_in[3];
    const float* lW2 = (const float*)d_in[4];
    const float* lb2 = (const float*)d_in[5];
    const float* lW3 = (const float*)d_in[6];
    const float* lb3 = (const float*)d_in[7];
    const float* gW1 = (const float*)d_in[8];
    const float* gb1 = (const float*)d_in[9];
    const float* gW2 = (const float*)d_in[10];
    const float* gb2 = (const float*)d_in[11];
    const float* gW3 = (const float*)d_in[12];
    const float* gb3 = (const float*)d_in[13];
    float* out = (float*)d_out;

    float* agg = (float*)d_ws;                                  // [4096][128] fp32 = 2 MB
    u16* w1t = (u16*)((char*)d_ws + (size_t)NUM_ELEC * EMB * 4);
    u16* w2t = w1t + 128 * 32;
    u16* w3t = w2t + 128 * 128;

    hipMemsetAsync(d_ws, 0, (size_t)NUM_ELEC * EMB * sizeof(float), stream);
    prep_weights<<<64, 256, 0, stream>>>(lW1, lW2, lW3, w1t, w2t, w3t);
    local_fused<<<N_VOTERS / 64, 256, 0, stream>>>(x, idx, lb1, lb2, lb3, w1t, w2t, w3t, agg);
    global_mlp<<<NUM_ELEC / 8, 256, 0, stream>>>(agg, gW1, gb1, gW2, gb2, gW3, gb3, out);
}